// Round 3
// baseline (638.642 us; speedup 1.0000x reference)
//
#include <hip/hip_runtime.h>

// Spiking NN collapses to 3 dependent masked binary matvecs (input drive is
// nonzero only at t=0; decaying membranes can never re-cross threshold):
//   enc = (u < x);  s0 = (W0*M0)@enc > 1;  s1 = (W1*M1)@s0 > 1;
//   out = ((W2*M2)@s1 > 1) ? 1/time_steps : 0
// HBM-bound: 384 MB streamed once (~half L3-resident across bench iters).
// v4: v3's fused+barrier structure was latency-bound (575 GB/s, VALU 2%,
// VGPR=36 -> ~2 loads in flight). Fix: drop nontemporal loads (back to the
// round-0 warm-L2 path) and force MLP with an explicit 4-stage prefetch
// pipeline (12 independent 16B loads in flight per wave), since
// launch_bounds(256,4) must stay to guarantee barrier co-residency.

constexpr int N = 4096;
constexpr int NBLOCKS = N / 4;   // 1024 = full-machine residency at 4 blk/CU
constexpr int NITER = N / 4 / 64;  // 16
constexpr int PF = 4;              // prefetch pipeline depth
typedef float f32x4 __attribute__((ext_vector_type(4)));

__device__ __forceinline__ void grid_barrier(int* cnt)
{
    __syncthreads();                       // drains this block's stores
    if (threadIdx.x == 0) {
        __threadfence();                   // release: L2 writeback (agent scope)
        atomicAdd(cnt, 1);                 // device-scope RMW at coherence point
        while (__hip_atomic_load(cnt, __ATOMIC_RELAXED,
                                 __HIP_MEMORY_SCOPE_AGENT) < NBLOCKS)
            __builtin_amdgcn_s_sleep(2);
        __threadfence();                   // acquire: invalidate stale caches
    }
    __syncthreads();
}

template <bool ENCODE, bool FINAL>
__device__ __forceinline__ void snn_phase(
    const float* __restrict__ W, const float* __restrict__ Mk,
    const float* __restrict__ S, const float* __restrict__ U,
    const int* __restrict__ t_steps, float* __restrict__ out,
    const int row, const int lane)
{
    const f32x4* W4 = reinterpret_cast<const f32x4*>(W + (size_t)row * N);
    const f32x4* M4 = reinterpret_cast<const f32x4*>(Mk + (size_t)row * N);
    const f32x4* S4 = reinterpret_cast<const f32x4*>(S);
    const f32x4* U4 = reinterpret_cast<const f32x4*>(U);

    // Explicit PF-deep software pipeline. All indices into the stage arrays
    // are compile-time constants after full unroll (no scratch spill).
    f32x4 wb[PF], mb[PF], sb[PF], ub[PF];
#pragma unroll
    for (int p = 0; p < PF; ++p) {
        const int idx = p * 64 + lane;
        wb[p] = W4[idx];
        mb[p] = M4[idx];
        sb[p] = S4[idx];
        if (ENCODE) ub[p] = U4[idx];
    }

    // 4 independent f64 chains: 16-deep each instead of one 64-deep chain.
    double a0 = 0.0, a1 = 0.0, a2 = 0.0, a3 = 0.0;
#pragma unroll
    for (int it = 0; it < NITER; ++it) {
        const int slot = it % PF;          // constant after unroll
        f32x4 w = wb[slot];
        f32x4 m = mb[slot];
        f32x4 s = sb[slot];
        f32x4 uu;
        if (ENCODE) uu = ub[slot];

        if (it + PF < NITER) {             // issue next loads before consuming
            const int idx = (it + PF) * 64 + lane;
            wb[slot] = W4[idx];
            mb[slot] = M4[idx];
            sb[slot] = S4[idx];
            if (ENCODE) ub[slot] = U4[idx];
        }

        if (ENCODE) {
            s.x = (uu.x < s.x) ? 1.0f : 0.0f;
            s.y = (uu.y < s.y) ? 1.0f : 0.0f;
            s.z = (uu.z < s.z) ? 1.0f : 0.0f;
            s.w = (uu.w < s.w) ? 1.0f : 0.0f;
        }
        // m and s are exact {0,1}; w*(m*s) is exact in f64 -> near-exact sum
        a0 = fma((double)w.x, (double)(m.x * s.x), a0);
        a1 = fma((double)w.y, (double)(m.y * s.y), a1);
        a2 = fma((double)w.z, (double)(m.z * s.z), a2);
        a3 = fma((double)w.w, (double)(m.w * s.w), a3);
    }
    double acc = (a0 + a1) + (a2 + a3);
#pragma unroll
    for (int off = 32; off > 0; off >>= 1)
        acc += __shfl_down(acc, off, 64);

    if (lane == 0) {
        if (FINAL) {
            out[row] = (acc > 1.0) ? (1.0f / (float)t_steps[0]) : 0.0f;
        } else {
            out[row] = (acc > 1.0) ? 1.0f : 0.0f;
        }
    }
}

// 1024 blocks x 256 threads; launch_bounds(256,4) caps VGPR at 128 so all
// 1024 blocks are co-resident (4 blocks/CU x 256 CU): barrier cannot deadlock.
__global__ __launch_bounds__(256, 4) void snn_fused(
    const float* __restrict__ x,  const float* __restrict__ u,
    const float* __restrict__ W0, const float* __restrict__ W1,
    const float* __restrict__ W2, const float* __restrict__ M0,
    const float* __restrict__ M1, const float* __restrict__ M2,
    const int* __restrict__ t_steps, float* __restrict__ out,
    float* __restrict__ s0, float* __restrict__ s1, int* bar)
{
    const int lane = threadIdx.x & 63;
    const int wave = threadIdx.x >> 6;
    const int row  = (blockIdx.x << 2) | wave;          // 1 wave per row

    snn_phase<true,  false>(W0, M0, x,  u,       nullptr, s0, row, lane);
    grid_barrier(bar + 0);
    snn_phase<false, false>(W1, M1, s0, nullptr, nullptr, s1, row, lane);
    grid_barrier(bar + 64);                             // separate cacheline
    snn_phase<false, true >(W2, M2, s1, nullptr, t_steps, out, row, lane);
}

extern "C" void kernel_launch(void* const* d_in, const int* in_sizes, int n_in,
                              void* d_out, int out_size, void* d_ws, size_t ws_size,
                              hipStream_t stream)
{
    const float* x  = (const float*)d_in[0];
    const float* u  = (const float*)d_in[1];
    const float* W0 = (const float*)d_in[2];
    const float* W1 = (const float*)d_in[3];
    const float* W2 = (const float*)d_in[4];
    const float* M0 = (const float*)d_in[5];
    const float* M1 = (const float*)d_in[6];
    const float* M2 = (const float*)d_in[7];
    const int* t_steps = (const int*)d_in[8];
    float* out = (float*)d_out;

    float* s0 = (float*)d_ws;           // 4096 floats, fully rewritten each call
    float* s1 = s0 + N;                 // 4096 floats
    int*  bar = (int*)(s1 + N);         // barrier counters

    // Workspace is re-poisoned between iterations: re-zero barrier counters
    // every call (capture-legal stream op).
    hipMemsetAsync(bar, 0, 128 * sizeof(int), stream);

    snn_fused<<<dim3(NBLOCKS), dim3(256), 0, stream>>>(
        x, u, W0, W1, W2, M0, M1, M2, t_steps, out, s0, s1, bar);
}

// Round 4
// 345.543 us; speedup vs baseline: 1.8482x; 1.8482x over previous
//
#include <hip/hip_runtime.h>

// Spiking NN collapses to 3 dependent masked binary matvecs (input drive is
// nonzero only at t=0; decaying membranes can never re-cross threshold):
//   enc = (u < x);  s0 = (W0*M0)@enc > 1;  s1 = (W1*M1)@s0 > 1;
//   out = ((W2*M2)@s1 > 1) ? 1/time_steps : 0
// HBM-bound: 384 MB of W+M streamed once. v5: fused-barrier experiments
// (v3/v4) were strictly dominated -- the launch_bounds(256,4) co-residency
// constraint capped in-flight loads (575-690 GB/s, scratch spills). Revert
// to 3 plain dispatches (graph replay makes gaps ~free; 343 us baseline)
// and raise per-layer MLP instead: half-row per wave -> 2x waves (8192),
// 8-deep fully-unrolled load run per wave, f64 partials combined via LDS.

constexpr int N = 4096;
typedef float f32x4 __attribute__((ext_vector_type(4)));

template <bool ENCODE, bool FINAL>
__global__ __launch_bounds__(256) void snn_layer(
    const float* __restrict__ W, const float* __restrict__ Mk,
    const float* __restrict__ S, const float* __restrict__ U,
    const int* __restrict__ t_steps, float* __restrict__ out)
{
    const int lane = threadIdx.x & 63;
    const int wave = threadIdx.x >> 6;
    const int row  = (blockIdx.x << 1) | (wave >> 1);   // 2 rows per block
    const int half = wave & 1;                          // 2 waves per row

    const f32x4* W4 = reinterpret_cast<const f32x4*>(W + (size_t)row * N);
    const f32x4* M4 = reinterpret_cast<const f32x4*>(Mk + (size_t)row * N);
    const f32x4* S4 = reinterpret_cast<const f32x4*>(S);
    const f32x4* U4 = reinterpret_cast<const f32x4*>(U);

    const int base = half * (N / 8);                    // float4 offset: 0 or 512

    // 4 independent f64 chains, 8 iterations each, fully unrolled; no
    // launch_bounds min-occupancy so the compiler can hoist all loads.
    double a0 = 0.0, a1 = 0.0, a2 = 0.0, a3 = 0.0;
#pragma unroll
    for (int it = 0; it < N / 8 / 64; ++it) {           // 8 iterations
        const int idx = base + it * 64 + lane;          // coalesced 1 KB/wave
        f32x4 w = W4[idx];
        f32x4 m = M4[idx];
        f32x4 s = S4[idx];                              // hot in L1/L2 (16 KB)
        if (ENCODE) {
            f32x4 uu = U4[idx];
            s.x = (uu.x < s.x) ? 1.0f : 0.0f;
            s.y = (uu.y < s.y) ? 1.0f : 0.0f;
            s.z = (uu.z < s.z) ? 1.0f : 0.0f;
            s.w = (uu.w < s.w) ? 1.0f : 0.0f;
        }
        // m and s are exact {0,1}; w*(m*s) is exact in f64 -> near-exact sum
        a0 = fma((double)w.x, (double)(m.x * s.x), a0);
        a1 = fma((double)w.y, (double)(m.y * s.y), a1);
        a2 = fma((double)w.z, (double)(m.z * s.z), a2);
        a3 = fma((double)w.w, (double)(m.w * s.w), a3);
    }
    double acc = (a0 + a1) + (a2 + a3);
#pragma unroll
    for (int off = 32; off > 0; off >>= 1)
        acc += __shfl_down(acc, off, 64);

    // Combine the two half-row partials per row through LDS.
    __shared__ double part[4];
    if (lane == 0) part[wave] = acc;
    __syncthreads();

    // wave0 lane0 -> row (blockIdx<<1), wave2 lane0 -> row (blockIdx<<1)|1
    if (lane == 0 && half == 0) {
        const double tot = part[wave] + part[wave | 1];
        if (FINAL) {
            out[row] = (tot > 1.0) ? (1.0f / (float)t_steps[0]) : 0.0f;
        } else {
            out[row] = (tot > 1.0) ? 1.0f : 0.0f;
        }
    }
}

extern "C" void kernel_launch(void* const* d_in, const int* in_sizes, int n_in,
                              void* d_out, int out_size, void* d_ws, size_t ws_size,
                              hipStream_t stream)
{
    const float* x  = (const float*)d_in[0];
    const float* u  = (const float*)d_in[1];
    const float* W0 = (const float*)d_in[2];
    const float* W1 = (const float*)d_in[3];
    const float* W2 = (const float*)d_in[4];
    const float* M0 = (const float*)d_in[5];
    const float* M1 = (const float*)d_in[6];
    const float* M2 = (const float*)d_in[7];
    const int* t_steps = (const int*)d_in[8];
    float* out = (float*)d_out;

    float* s0 = (float*)d_ws;       // 4096 floats, fully rewritten each call
    float* s1 = s0 + N;             // 4096 floats

    dim3 grid(N / 2), block(256);   // 2048 blocks: 2 rows/block, 2 waves/row
    snn_layer<true,  false><<<grid, block, 0, stream>>>(W0, M0, x,  u,       nullptr, s0);
    snn_layer<false, false><<<grid, block, 0, stream>>>(W1, M1, s0, nullptr, nullptr, s1);
    snn_layer<false, true ><<<grid, block, 0, stream>>>(W2, M2, s1, nullptr, t_steps, out);
}

// Round 5
// 344.721 us; speedup vs baseline: 1.8526x; 1.0024x over previous
//
#include <hip/hip_runtime.h>

// Spiking NN collapses to 3 dependent masked binary matvecs (input drive is
// nonzero only at t=0; decaying membranes can never re-cross threshold):
//   enc = (u < x);  s0 = (W0*M0)@enc > 1;  s1 = (W1*M1)@s0 > 1;
//   out = ((W2*M2)@s1 > 1) ? 1/time_steps : 0
// HBM-bound: 384 MB of W+M streamed once per call. v6: v0/v5 both measured
// ~3.4 TB/s effective -- Little's law: VGPR-buffered loads give only ~2.3 KB
// in flight per CU vs the ~19 KB needed for ~6.9 TB/s at ~700 ns latency.
// Fix: stage W/M through LDS via global_load_lds (async DMA, no VGPR dest,
// vmcnt-tracked). Each wave issues its full 16 KB half-row (16 x 1 KB chunk
// loads) before waiting -> 8 waves/CU x 16 KB = 128 KB/CU in flight.
// Chunks are wave-private: no __syncthreads in the streaming path.

constexpr int N = 4096;
typedef float f32x4 __attribute__((ext_vector_type(4)));

#define GLOBAL_AS __attribute__((address_space(1)))
#define LDS_AS    __attribute__((address_space(3)))

template <bool ENCODE, bool FINAL>
__global__ __launch_bounds__(256) void snn_layer(
    const float* __restrict__ W, const float* __restrict__ Mk,
    const float* __restrict__ S, const float* __restrict__ U,
    const int* __restrict__ t_steps, float* __restrict__ out)
{
    const int lane = threadIdx.x & 63;
    const int wave = threadIdx.x >> 6;
    const int r    = wave >> 1;                         // row within block
    const int h    = wave & 1;                          // half of the row
    const int row  = (blockIdx.x << 1) | r;             // 2 rows per block

    // [row-in-block][half][f32x4]: 8 KB per wave per stream; 64 KB/block
    // -> 2 blocks/CU (LDS 160 KB), 8 waves/CU.
    __shared__ f32x4 sW[2][2][512];
    __shared__ f32x4 sM[2][2][512];

    const f32x4* W4 = reinterpret_cast<const f32x4*>(W + (size_t)row * N);
    const f32x4* M4 = reinterpret_cast<const f32x4*>(Mk + (size_t)row * N);
    const f32x4* S4 = reinterpret_cast<const f32x4*>(S);
    const f32x4* U4 = reinterpret_cast<const f32x4*>(U);

    const int gb = h * 512;                             // f32x4 offset of half

    // Issue all 16 chunk DMAs back-to-back: 16 KB in flight per wave, zero
    // destination VGPRs. LDS dest is wave-uniform base + lane*16 (HW rule),
    // which matches the linear layout exactly.
#pragma unroll
    for (int c = 0; c < 8; ++c) {
        __builtin_amdgcn_global_load_lds(
            (const GLOBAL_AS void*)&W4[gb + c * 64 + lane],
            (LDS_AS void*)&sW[r][h][c * 64], 16, 0, 0);
        __builtin_amdgcn_global_load_lds(
            (const GLOBAL_AS void*)&M4[gb + c * 64 + lane],
            (LDS_AS void*)&sM[r][h][c * 64], 16, 0, 0);
    }

    // While the DMAs fly, pull the (L1/L2-hot, 16 KB) spike vector into
    // registers and apply the encoder.
    f32x4 sv[8];
#pragma unroll
    for (int c = 0; c < 8; ++c) {
        const int idx = gb + c * 64 + lane;
        f32x4 s = S4[idx];
        if (ENCODE) {
            f32x4 uu = U4[idx];
            s.x = (uu.x < s.x) ? 1.0f : 0.0f;
            s.y = (uu.y < s.y) ? 1.0f : 0.0f;
            s.z = (uu.z < s.z) ? 1.0f : 0.0f;
            s.w = (uu.w < s.w) ? 1.0f : 0.0f;
        }
        sv[c] = s;
    }

    // Wave-local drain of the DMA queue (also covers the S/U loads above).
    asm volatile("s_waitcnt vmcnt(0)" ::: "memory");

    // 4 independent f64 chains; m,s exact {0,1} -> w*(m*s) exact in f64.
    double a0 = 0.0, a1 = 0.0, a2 = 0.0, a3 = 0.0;
#pragma unroll
    for (int c = 0; c < 8; ++c) {
        f32x4 w = sW[r][h][c * 64 + lane];
        f32x4 m = sM[r][h][c * 64 + lane];
        f32x4 s = sv[c];
        a0 = fma((double)w.x, (double)(m.x * s.x), a0);
        a1 = fma((double)w.y, (double)(m.y * s.y), a1);
        a2 = fma((double)w.z, (double)(m.z * s.z), a2);
        a3 = fma((double)w.w, (double)(m.w * s.w), a3);
    }
    double acc = (a0 + a1) + (a2 + a3);
#pragma unroll
    for (int off = 32; off > 0; off >>= 1)
        acc += __shfl_down(acc, off, 64);

    // Combine the two half-row partials per row.
    __shared__ double part[4];
    if (lane == 0) part[wave] = acc;
    __syncthreads();

    if (lane == 0 && h == 0) {
        const double tot = part[wave] + part[wave | 1];
        if (FINAL) {
            out[row] = (tot > 1.0) ? (1.0f / (float)t_steps[0]) : 0.0f;
        } else {
            out[row] = (tot > 1.0) ? 1.0f : 0.0f;
        }
    }
}

extern "C" void kernel_launch(void* const* d_in, const int* in_sizes, int n_in,
                              void* d_out, int out_size, void* d_ws, size_t ws_size,
                              hipStream_t stream)
{
    const float* x  = (const float*)d_in[0];
    const float* u  = (const float*)d_in[1];
    const float* W0 = (const float*)d_in[2];
    const float* W1 = (const float*)d_in[3];
    const float* W2 = (const float*)d_in[4];
    const float* M0 = (const float*)d_in[5];
    const float* M1 = (const float*)d_in[6];
    const float* M2 = (const float*)d_in[7];
    const int* t_steps = (const int*)d_in[8];
    float* out = (float*)d_out;

    float* s0 = (float*)d_ws;       // 4096 floats, fully rewritten each call
    float* s1 = s0 + N;             // 4096 floats

    dim3 grid(N / 2), block(256);   // 2048 blocks: 2 rows/block, 2 waves/row
    snn_layer<true,  false><<<grid, block, 0, stream>>>(W0, M0, x,  u,       nullptr, s0);
    snn_layer<false, false><<<grid, block, 0, stream>>>(W1, M1, s0, nullptr, nullptr, s1);
    snn_layer<false, true ><<<grid, block, 0, stream>>>(W2, M2, s1, nullptr, t_steps, out);
}